// Round 1
// baseline (175.557 us; speedup 1.0000x reference)
//
#include <hip/hip_runtime.h>
#include <hip/hip_bf16.h>

// LinearAttention fused pipeline for MI355X (gfx950).
// Workspace layout (bytes), total 75,563,008 (~72 MB):
//   [0          , 16777216 )  xn  bf16 [16384][512]   (reused later as QS)
//   [16777216   , 18350080 )  WqkvT bf16 [1536][512]
//   [18350080   , 68681728 )  qkv bf16 [16384][1536]  (reused later as y f32 [16384][512])
//   [68681728   , 72876032 )  pctx f32 [256][64][64]
//   [72876032   , 72941568 )  pden f32 [256][64]
//   [72941568   , 73465856 )  ctx  f32 [32][64][64]
//   [73465856   , 75563008 )  W2T  bf16 [4][512][512]

typedef __attribute__((ext_vector_type(8))) __bf16 bf16x8;
typedef __attribute__((ext_vector_type(4))) __bf16 bf16x4;
typedef __attribute__((ext_vector_type(4))) float f32x4;

#define SQRT_DIM 22.627416997969522f

__device__ __forceinline__ void gload_lds16(const void* g, void* l) {
  __builtin_amdgcn_global_load_lds((__attribute__((address_space(1))) void*)g,
                                   (__attribute__((address_space(3))) void*)l, 16, 0, 0);
}

// ---------- K0: transpose w_qkv [512][1536] f32 -> WqkvT [1536][512] bf16
__global__ __launch_bounds__(256) void wqkv_transpose(const float* __restrict__ in,
                                                      __bf16* __restrict__ out) {
  int i = blockIdx.x * 256 + threadIdx.x;  // < 1536*512
  int n = i >> 9, k = i & 511;
  out[i] = (__bf16)in[k * 1536 + n];
}

// ---------- K1/K8: row L2-norm scale (x / max(||x||,1e-12) * w * sqrt(512))
template <int OUT_BF16>
__global__ __launch_bounds__(256) void rmsnorm_k(const float* __restrict__ x,
                                                 const float* __restrict__ w,
                                                 void* __restrict__ outv) {
  const int row = blockIdx.x * 4 + (threadIdx.x >> 6);
  const int lane = threadIdx.x & 63;
  const float4* xr = (const float4*)(x + (size_t)row * 512);
  float4 v0 = xr[lane], v1 = xr[lane + 64];
  float s = v0.x * v0.x + v0.y * v0.y + v0.z * v0.z + v0.w * v0.w +
            v1.x * v1.x + v1.y * v1.y + v1.z * v1.z + v1.w * v1.w;
#pragma unroll
  for (int m = 1; m < 64; m <<= 1) s += __shfl_xor(s, m);
  const float sc = SQRT_DIM / fmaxf(sqrtf(s), 1e-12f);
  const float4* wr4 = (const float4*)w;
  float4 w0 = wr4[lane], w1 = wr4[lane + 64];
  float o0 = v0.x * sc * w0.x, o1 = v0.y * sc * w0.y, o2 = v0.z * sc * w0.z,
        o3 = v0.w * sc * w0.w;
  float o4 = v1.x * sc * w1.x, o5 = v1.y * sc * w1.y, o6 = v1.z * sc * w1.z,
        o7 = v1.w * sc * w1.w;
  if (OUT_BF16) {
    __bf16* out = (__bf16*)outv + (size_t)row * 512;
    bf16x4 a, b2;
    a[0] = (__bf16)o0; a[1] = (__bf16)o1; a[2] = (__bf16)o2; a[3] = (__bf16)o3;
    b2[0] = (__bf16)o4; b2[1] = (__bf16)o5; b2[2] = (__bf16)o6; b2[3] = (__bf16)o7;
    *(bf16x4*)(out + lane * 4) = a;
    *(bf16x4*)(out + 256 + lane * 4) = b2;
  } else {
    float* out = (float*)outv + (size_t)row * 512;
    ((float4*)out)[lane] = make_float4(o0, o1, o2, o3);
    ((float4*)out)[lane + 64] = make_float4(o4, o5, o6, o7);
  }
}

// ---------- GEMM (m97-style): C[M,N] = A[M,K] * BT[N,K]^T, 128x128 tile, BK=64
template <int OUTF32, int BIAS>
__global__ __launch_bounds__(256) void gemm_bt128(const __bf16* __restrict__ A,
                                                  const __bf16* __restrict__ BT,
                                                  void* __restrict__ Cout,
                                                  const float* __restrict__ bias,
                                                  int M, int Nn, int K,
                                                  size_t bt_bstride) {
  __shared__ __bf16 As[128 * 64];
  __shared__ __bf16 Bs[128 * 64];
  const int tid = threadIdx.x;
  const int lane = tid & 63;
  const int wave = tid >> 6;
  const int wr = (wave >> 1) * 64, wc = (wave & 1) * 64;
  const int m0 = blockIdx.y * 128, n0 = blockIdx.x * 128;
  const __bf16* bt = BT + (size_t)(m0 >> 12) * bt_bstride;  // per-batch B (4096 rows/batch)
  const int l15 = lane & 15, lg = lane >> 4;
  f32x4 acc[4][4] = {};
  for (int k0 = 0; k0 < K; k0 += 64) {
#pragma unroll
    for (int it = 0; it < 4; ++it) {
      int flat = it * 256 + tid;
      int row = flat >> 3;           // 8 threads per 128B row
      int cb = (flat & 7) * 16;      // byte offset within row
      gload_lds16((const char*)(A + (size_t)(m0 + row) * K + k0) + cb,
                  (char*)As + flat * 16);
      gload_lds16((const char*)(bt + (size_t)(n0 + row) * K + k0) + cb,
                  (char*)Bs + flat * 16);
    }
    __syncthreads();
#pragma unroll
    for (int kk = 0; kk < 2; ++kk) {
      bf16x8 af[4], bfr[4];
#pragma unroll
      for (int i = 0; i < 4; ++i) {
        af[i] = *(const bf16x8*)(As + (wr + i * 16 + l15) * 64 + kk * 32 + lg * 8);
        bfr[i] = *(const bf16x8*)(Bs + (wc + i * 16 + l15) * 64 + kk * 32 + lg * 8);
      }
#pragma unroll
      for (int mi = 0; mi < 4; ++mi)
#pragma unroll
        for (int ni = 0; ni < 4; ++ni)
          acc[mi][ni] = __builtin_amdgcn_mfma_f32_16x16x32_bf16(
              af[mi], bfr[ni], acc[mi][ni], 0, 0, 0);
    }
    __syncthreads();
  }
#pragma unroll
  for (int mi = 0; mi < 4; ++mi)
#pragma unroll
    for (int ni = 0; ni < 4; ++ni) {
      int col = n0 + wc + ni * 16 + l15;
      float bv = BIAS ? bias[col] : 0.0f;
#pragma unroll
      for (int r = 0; r < 4; ++r) {
        int rw = m0 + wr + mi * 16 + lg * 4 + r;
        float v = acc[mi][ni][r] + bv;
        if (OUTF32)
          ((float*)Cout)[(size_t)rw * Nn + col] = v;
        else
          ((__bf16*)Cout)[(size_t)rw * Nn + col] = (__bf16)v;
      }
    }
}

// ---------- K3: partial context: pctx[wg] = sum_tokens exp(k[d])*v[e]; pden = sum exp(k[d])
__global__ __launch_bounds__(256) void ctx_partial(const __bf16* __restrict__ qkv,
                                                   float* __restrict__ pctx,
                                                   float* __restrict__ pden) {
  const int wg = blockIdx.x;  // 0..255 : bh*8 + chunk
  const int bh = wg >> 3, chunk = wg & 7;
  const int b = bh >> 3, h = bh & 7;
  const int tid = threadIdx.x;
  __shared__ float ek[16][64];
  __shared__ float vv[16][64];
  float acc[4][4] = {};
  float dsum = 0.0f;
  const int td = (tid >> 4) * 4, te = (tid & 15) * 4;
  const int tokc = tid >> 4, rr = tid & 15;
  for (int t0 = 0; t0 < 512; t0 += 16) {
    __syncthreads();
    {
      int tok = b * 4096 + chunk * 512 + t0 + tokc;
      const __bf16* base = qkv + (size_t)tok * 1536 + 512 + h * 64;  // k block
      if (rr < 8) {
        bf16x8 kv = *(const bf16x8*)(base + rr * 8);
#pragma unroll
        for (int j = 0; j < 8; ++j) ek[tokc][rr * 8 + j] = __expf((float)kv[j]);
      } else {
        bf16x8 vx = *(const bf16x8*)(base + 512 + (rr - 8) * 8);  // v block
#pragma unroll
        for (int j = 0; j < 8; ++j) vv[tokc][(rr - 8) * 8 + j] = (float)vx[j];
      }
    }
    __syncthreads();
#pragma unroll
    for (int t = 0; t < 16; ++t) {
      float4 a4 = *(const float4*)&ek[t][td];
      float4 b4 = *(const float4*)&vv[t][te];
      float aa[4] = {a4.x, a4.y, a4.z, a4.w};
      float bb[4] = {b4.x, b4.y, b4.z, b4.w};
#pragma unroll
      for (int i = 0; i < 4; ++i)
#pragma unroll
        for (int j = 0; j < 4; ++j) acc[i][j] += aa[i] * bb[j];
    }
    if (tid < 64) {
#pragma unroll
      for (int t = 0; t < 16; ++t) dsum += ek[t][tid];
    }
  }
  float* op = pctx + (size_t)wg * 4096;
#pragma unroll
  for (int i = 0; i < 4; ++i)
#pragma unroll
    for (int j = 0; j < 4; ++j) op[(td + i) * 64 + te + j] = acc[i][j];
  if (tid < 64) pden[wg * 64 + tid] = dsum;
}

// ---------- K4: finalize ctx with memory-KV and softmax denominator
__global__ __launch_bounds__(256) void ctx_final(const float* __restrict__ pctx,
                                                 const float* __restrict__ pden,
                                                 const float* __restrict__ memkv,
                                                 float* __restrict__ ctx) {
  const int bh = blockIdx.x;  // 0..31
  const int h = bh & 7;
  const int tid = threadIdx.x;
  __shared__ float emk[64][8], mvl[64][8], den[64];
  if (tid < 64) {
    float d = 0.0f;
#pragma unroll
    for (int m = 0; m < 8; ++m) {
      float e = __expf(memkv[(size_t)h * 512 + tid * 8 + m]);  // mem_kv[0][h][d][m]
      emk[tid][m] = e;
      d += e;
      mvl[tid][m] = memkv[4096 + (size_t)h * 512 + tid * 8 + m];  // mem_kv[1][h][e][m]
    }
#pragma unroll
    for (int c = 0; c < 8; ++c) d += pden[((size_t)bh * 8 + c) * 64 + tid];
    den[tid] = d;
  }
  __syncthreads();
  const int td = (tid >> 4) * 4, te = (tid & 15) * 4;
#pragma unroll
  for (int i = 0; i < 4; ++i) {
    int dd = td + i;
    float invd = 1.0f / den[dd];
#pragma unroll
    for (int j = 0; j < 4; ++j) {
      int e = te + j;
      float s = 0.0f;
#pragma unroll
      for (int m = 0; m < 8; ++m) s += emk[dd][m] * mvl[e][m];
#pragma unroll
      for (int c = 0; c < 8; ++c)
        s += pctx[((size_t)bh * 8 + c) * 4096 + dd * 64 + e];
      ctx[(size_t)bh * 4096 + dd * 64 + e] = s * invd;
    }
  }
}

// ---------- K5: fold ctx into w_out: W2T[b][j][h*64+d] = sum_e ctx[b,h,d,e]*w_out[h*64+e][j]
__global__ __launch_bounds__(256) void make_w2t(const float* __restrict__ ctx,
                                                const float* __restrict__ wout,
                                                __bf16* __restrict__ W2T) {
  const int wg = blockIdx.x;  // b*32 + h*4 + jc
  const int b = wg >> 5, h = (wg >> 2) & 7, jc = wg & 3;
  const int j0 = jc * 128;
  const int tid = threadIdx.x;
  __shared__ float cs[64][65];
  __shared__ float wo[64][128];
  const float* ch = ctx + ((size_t)b * 8 + h) * 4096;
#pragma unroll
  for (int it = 0; it < 16; ++it) {
    int flat = it * 256 + tid;  // 4096
    cs[flat >> 6][flat & 63] = ch[flat];
  }
#pragma unroll
  for (int it = 0; it < 32; ++it) {
    int flat = it * 256 + tid;  // 8192
    int e = flat >> 7, j = flat & 127;
    wo[e][j] = wout[(size_t)(h * 64 + e) * 512 + j0 + j];
  }
  __syncthreads();
  const int d = tid & 63;
  const int jg = (tid >> 6) * 32;
  for (int jj = 0; jj < 32; ++jj) {
    int j = jg + jj;
    float s = 0.0f;
#pragma unroll
    for (int e = 0; e < 64; ++e) s += cs[d][e] * wo[e][j];
    W2T[(size_t)b * 262144 + (size_t)(j0 + j) * 512 + h * 64 + d] = (__bf16)s;
  }
}

// ---------- K6: q feature-softmax (over c=64 per (t,h)) * C^-0.5
__global__ __launch_bounds__(256) void q_softmax(const __bf16* __restrict__ qkv,
                                                 __bf16* __restrict__ QS) {
  const int gid = blockIdx.x * 256 + threadIdx.x;
  const int g = gid >> 4;  // pair (t,h)
  const int l = gid & 15;
  const int t = g >> 3, h = g & 7;
  bf16x4 v = *(const bf16x4*)(qkv + (size_t)t * 1536 + h * 64 + l * 4);
  float f0 = (float)v[0], f1 = (float)v[1], f2 = (float)v[2], f3 = (float)v[3];
  float mx = fmaxf(fmaxf(f0, f1), fmaxf(f2, f3));
#pragma unroll
  for (int m = 1; m < 16; m <<= 1) mx = fmaxf(mx, __shfl_xor(mx, m));
  float e0 = __expf(f0 - mx), e1 = __expf(f1 - mx), e2 = __expf(f2 - mx),
        e3 = __expf(f3 - mx);
  float s = e0 + e1 + e2 + e3;
#pragma unroll
  for (int m = 1; m < 16; m <<= 1) s += __shfl_xor(s, m);
  float inv = 0.125f / s;  // * C^-0.5 (=1/8)
  bf16x4 o;
  o[0] = (__bf16)(e0 * inv); o[1] = (__bf16)(e1 * inv);
  o[2] = (__bf16)(e2 * inv); o[3] = (__bf16)(e3 * inv);
  *(bf16x4*)(QS + (size_t)t * 512 + h * 64 + l * 4) = o;
}

extern "C" void kernel_launch(void* const* d_in, const int* in_sizes, int n_in,
                              void* d_out, int out_size, void* d_ws, size_t ws_size,
                              hipStream_t stream) {
  const float* x = (const float*)d_in[0];
  const float* norm_w = (const float*)d_in[1];
  const float* w_qkv = (const float*)d_in[2];
  const float* mem_kv = (const float*)d_in[3];
  const float* w_out = (const float*)d_in[4];
  const float* b_out = (const float*)d_in[5];
  const float* onw = (const float*)d_in[6];

  char* ws = (char*)d_ws;
  __bf16* xn = (__bf16*)(ws + 0);              // 16 MB
  __bf16* WqkvT = (__bf16*)(ws + 16777216);    // 1.5 MB
  __bf16* qkv = (__bf16*)(ws + 18350080);      // 48 MB
  float* pctx = (float*)(ws + 68681728);       // 4 MB
  float* pden = (float*)(ws + 72876032);       // 64 KB
  float* ctx = (float*)(ws + 72941568);        // 512 KB
  __bf16* W2T = (__bf16*)(ws + 73465856);      // 2 MB
  __bf16* QS = xn;                             // reuse (xn dead after GEMM1)
  float* y = (float*)qkv;                      // reuse (qkv dead after q_softmax)

  wqkv_transpose<<<3072, 256, 0, stream>>>(w_qkv, WqkvT);
  rmsnorm_k<1><<<4096, 256, 0, stream>>>(x, norm_w, (void*)xn);
  gemm_bt128<0, 0><<<dim3(12, 128), 256, 0, stream>>>(xn, WqkvT, (void*)qkv,
                                                      nullptr, 16384, 1536, 512, 0);
  ctx_partial<<<256, 256, 0, stream>>>(qkv, pctx, pden);
  ctx_final<<<32, 256, 0, stream>>>(pctx, pden, mem_kv, ctx);
  make_w2t<<<128, 256, 0, stream>>>(ctx, w_out, W2T);
  q_softmax<<<8192, 256, 0, stream>>>(qkv, QS);
  gemm_bt128<1, 1><<<dim3(4, 128), 256, 0, stream>>>(QS, W2T, (void*)y, b_out,
                                                     16384, 512, 512, 262144);
  rmsnorm_k<0><<<4096, 256, 0, stream>>>(y, onw, d_out);
}

// Round 2
// 154.960 us; speedup vs baseline: 1.1329x; 1.1329x over previous
//
#include <hip/hip_runtime.h>
#include <hip/hip_bf16.h>

// LinearAttention fused pipeline for MI355X (gfx950).
// Workspace layout (bytes), total 71,565,312 (~68 MB):
//   region0 [0, 16777216): time-shared (stream-ordered):
//       xn  bf16 [16384][512]   (rmsnorm -> GEMM1)
//       pctx f32 [1024][64][64] (ctx_partial -> ctx_final)
//       QS  bf16 [16384][512]   (q_softmax -> GEMM2)
//   [16777216, 18350080)  WqkvT bf16 [1536][512]
//   [18350080, 68681728)  qkv bf16 [16384][1536]  (reused later as y f32 [16384][512])
//   [68681728, 68943872)  pden f32 [1024][64]
//   [68943872, 69468160)  ctx  f32 [32][64][64]
//   [69468160, 71565312)  W2T  bf16 [4][512][512]

typedef __attribute__((ext_vector_type(8))) __bf16 bf16x8;
typedef __attribute__((ext_vector_type(4))) __bf16 bf16x4;
typedef __attribute__((ext_vector_type(4))) float f32x4;

#define SQRT_DIM 22.627416997969522f

__device__ __forceinline__ void gload_lds16(const void* g, void* l) {
  __builtin_amdgcn_global_load_lds((__attribute__((address_space(1))) void*)g,
                                   (__attribute__((address_space(3))) void*)l, 16, 0, 0);
}

// ---------- K0: transpose w_qkv [512][1536] f32 -> WqkvT [1536][512] bf16
__global__ __launch_bounds__(256) void wqkv_transpose(const float* __restrict__ in,
                                                      __bf16* __restrict__ out) {
  int i = blockIdx.x * 256 + threadIdx.x;  // < 1536*512
  int n = i >> 9, k = i & 511;
  out[i] = (__bf16)in[k * 1536 + n];
}

// ---------- K1/K8: row L2-norm scale (x / max(||x||,1e-12) * w * sqrt(512))
template <int OUT_BF16>
__global__ __launch_bounds__(256) void rmsnorm_k(const float* __restrict__ x,
                                                 const float* __restrict__ w,
                                                 void* __restrict__ outv) {
  const int row = blockIdx.x * 4 + (threadIdx.x >> 6);
  const int lane = threadIdx.x & 63;
  const float4* xr = (const float4*)(x + (size_t)row * 512);
  float4 v0 = xr[lane], v1 = xr[lane + 64];
  float s = v0.x * v0.x + v0.y * v0.y + v0.z * v0.z + v0.w * v0.w +
            v1.x * v1.x + v1.y * v1.y + v1.z * v1.z + v1.w * v1.w;
#pragma unroll
  for (int m = 1; m < 64; m <<= 1) s += __shfl_xor(s, m);
  const float sc = SQRT_DIM / fmaxf(sqrtf(s), 1e-12f);
  const float4* wr4 = (const float4*)w;
  float4 w0 = wr4[lane], w1 = wr4[lane + 64];
  float o0 = v0.x * sc * w0.x, o1 = v0.y * sc * w0.y, o2 = v0.z * sc * w0.z,
        o3 = v0.w * sc * w0.w;
  float o4 = v1.x * sc * w1.x, o5 = v1.y * sc * w1.y, o6 = v1.z * sc * w1.z,
        o7 = v1.w * sc * w1.w;
  if (OUT_BF16) {
    __bf16* out = (__bf16*)outv + (size_t)row * 512;
    bf16x4 a, b2;
    a[0] = (__bf16)o0; a[1] = (__bf16)o1; a[2] = (__bf16)o2; a[3] = (__bf16)o3;
    b2[0] = (__bf16)o4; b2[1] = (__bf16)o5; b2[2] = (__bf16)o6; b2[3] = (__bf16)o7;
    *(bf16x4*)(out + lane * 4) = a;
    *(bf16x4*)(out + 256 + lane * 4) = b2;
  } else {
    float* out = (float*)outv + (size_t)row * 512;
    ((float4*)out)[lane] = make_float4(o0, o1, o2, o3);
    ((float4*)out)[lane + 64] = make_float4(o4, o5, o6, o7);
  }
}

// ---------- GEMM (m97-style): C[M,N] = A[M,K] * BT[N,K]^T, 128x128 tile, BK=64
template <int OUTF32, int BIAS>
__global__ __launch_bounds__(256) void gemm_bt128(const __bf16* __restrict__ A,
                                                  const __bf16* __restrict__ BT,
                                                  void* __restrict__ Cout,
                                                  const float* __restrict__ bias,
                                                  int M, int Nn, int K,
                                                  size_t bt_bstride) {
  __shared__ __bf16 As[128 * 64];
  __shared__ __bf16 Bs[128 * 64];
  const int tid = threadIdx.x;
  const int lane = tid & 63;
  const int wave = tid >> 6;
  const int wr = (wave >> 1) * 64, wc = (wave & 1) * 64;
  const int m0 = blockIdx.y * 128, n0 = blockIdx.x * 128;
  const __bf16* bt = BT + (size_t)(m0 >> 12) * bt_bstride;  // per-batch B (4096 rows/batch)
  const int l15 = lane & 15, lg = lane >> 4;
  f32x4 acc[4][4] = {};
  for (int k0 = 0; k0 < K; k0 += 64) {
#pragma unroll
    for (int it = 0; it < 4; ++it) {
      int flat = it * 256 + tid;
      int row = flat >> 3;           // 8 threads per 128B row
      int cb = (flat & 7) * 16;      // byte offset within row
      gload_lds16((const char*)(A + (size_t)(m0 + row) * K + k0) + cb,
                  (char*)As + flat * 16);
      gload_lds16((const char*)(bt + (size_t)(n0 + row) * K + k0) + cb,
                  (char*)Bs + flat * 16);
    }
    __syncthreads();
#pragma unroll
    for (int kk = 0; kk < 2; ++kk) {
      bf16x8 af[4], bfr[4];
#pragma unroll
      for (int i = 0; i < 4; ++i) {
        af[i] = *(const bf16x8*)(As + (wr + i * 16 + l15) * 64 + kk * 32 + lg * 8);
        bfr[i] = *(const bf16x8*)(Bs + (wc + i * 16 + l15) * 64 + kk * 32 + lg * 8);
      }
#pragma unroll
      for (int mi = 0; mi < 4; ++mi)
#pragma unroll
        for (int ni = 0; ni < 4; ++ni)
          acc[mi][ni] = __builtin_amdgcn_mfma_f32_16x16x32_bf16(
              af[mi], bfr[ni], acc[mi][ni], 0, 0, 0);
    }
    __syncthreads();
  }
#pragma unroll
  for (int mi = 0; mi < 4; ++mi)
#pragma unroll
    for (int ni = 0; ni < 4; ++ni) {
      int col = n0 + wc + ni * 16 + l15;
      float bv = BIAS ? bias[col] : 0.0f;
#pragma unroll
      for (int r = 0; r < 4; ++r) {
        int rw = m0 + wr + mi * 16 + lg * 4 + r;
        float v = acc[mi][ni][r] + bv;
        if (OUTF32)
          ((float*)Cout)[(size_t)rw * Nn + col] = v;
        else
          ((__bf16*)Cout)[(size_t)rw * Nn + col] = (__bf16)v;
      }
    }
}

// ---------- K3: partial context: pctx[wg] = sum_tokens exp(k[d])*v[e]; pden = sum exp(k[d])
// 1024 blocks = bh(32) x chunk(32), 128 tokens per chunk.
__global__ __launch_bounds__(256) void ctx_partial(const __bf16* __restrict__ qkv,
                                                   float* __restrict__ pctx,
                                                   float* __restrict__ pden) {
  const int wg = blockIdx.x;  // 0..1023 : bh*32 + chunk
  const int bh = wg >> 5, chunk = wg & 31;
  const int b = bh >> 3, h = bh & 7;
  const int tid = threadIdx.x;
  __shared__ float ek[16][64];
  __shared__ float vv[16][64];
  float acc[4][4] = {};
  float dsum = 0.0f;
  const int td = (tid >> 4) * 4, te = (tid & 15) * 4;
  const int tokc = tid >> 4, rr = tid & 15;
  for (int t0 = 0; t0 < 128; t0 += 16) {
    __syncthreads();
    {
      int tok = b * 4096 + chunk * 128 + t0 + tokc;
      const __bf16* base = qkv + (size_t)tok * 1536 + 512 + h * 64;  // k block
      if (rr < 8) {
        bf16x8 kv = *(const bf16x8*)(base + rr * 8);
#pragma unroll
        for (int j = 0; j < 8; ++j) ek[tokc][rr * 8 + j] = __expf((float)kv[j]);
      } else {
        bf16x8 vx = *(const bf16x8*)(base + 512 + (rr - 8) * 8);  // v block
#pragma unroll
        for (int j = 0; j < 8; ++j) vv[tokc][(rr - 8) * 8 + j] = (float)vx[j];
      }
    }
    __syncthreads();
#pragma unroll
    for (int t = 0; t < 16; ++t) {
      float4 a4 = *(const float4*)&ek[t][td];
      float4 b4 = *(const float4*)&vv[t][te];
      float aa[4] = {a4.x, a4.y, a4.z, a4.w};
      float bb[4] = {b4.x, b4.y, b4.z, b4.w};
#pragma unroll
      for (int i = 0; i < 4; ++i)
#pragma unroll
        for (int j = 0; j < 4; ++j) acc[i][j] += aa[i] * bb[j];
    }
    if (tid < 64) {
#pragma unroll
      for (int t = 0; t < 16; ++t) dsum += ek[t][tid];
    }
  }
  float* op = pctx + (size_t)wg * 4096;
#pragma unroll
  for (int i = 0; i < 4; ++i)
#pragma unroll
    for (int j = 0; j < 4; ++j) op[(td + i) * 64 + te + j] = acc[i][j];
  if (tid < 64) pden[wg * 64 + tid] = dsum;
}

// ---------- K4: finalize ctx with memory-KV and softmax denominator (32 chunks)
__global__ __launch_bounds__(256) void ctx_final(const float* __restrict__ pctx,
                                                 const float* __restrict__ pden,
                                                 const float* __restrict__ memkv,
                                                 float* __restrict__ ctx) {
  const int bh = blockIdx.x;  // 0..31
  const int h = bh & 7;
  const int tid = threadIdx.x;
  __shared__ float emk[64][8], mvl[64][8], den[64];
  if (tid < 64) {
    float d = 0.0f;
#pragma unroll
    for (int m = 0; m < 8; ++m) {
      float e = __expf(memkv[(size_t)h * 512 + tid * 8 + m]);  // mem_kv[0][h][d][m]
      emk[tid][m] = e;
      d += e;
      mvl[tid][m] = memkv[4096 + (size_t)h * 512 + tid * 8 + m];  // mem_kv[1][h][e][m]
    }
#pragma unroll
    for (int c = 0; c < 32; ++c) d += pden[((size_t)bh * 32 + c) * 64 + tid];
    den[tid] = d;
  }
  __syncthreads();
  const int td = (tid >> 4) * 4, te = (tid & 15) * 4;
#pragma unroll
  for (int i = 0; i < 4; ++i) {
    int dd = td + i;
    float invd = 1.0f / den[dd];
#pragma unroll
    for (int j = 0; j < 4; ++j) {
      int e = te + j;
      float s = 0.0f;
#pragma unroll
      for (int m = 0; m < 8; ++m) s += emk[dd][m] * mvl[e][m];
#pragma unroll
      for (int c = 0; c < 32; ++c)
        s += pctx[((size_t)bh * 32 + c) * 4096 + dd * 64 + e];
      ctx[(size_t)bh * 4096 + dd * 64 + e] = s * invd;
    }
  }
}

// ---------- K5: fold ctx into w_out: W2T[b][j][h*64+d] = sum_e ctx[b,h,d,e]*w_out[h*64+e][j]
__global__ __launch_bounds__(256) void make_w2t(const float* __restrict__ ctx,
                                                const float* __restrict__ wout,
                                                __bf16* __restrict__ W2T) {
  const int wg = blockIdx.x;  // b*32 + h*4 + jc
  const int b = wg >> 5, h = (wg >> 2) & 7, jc = wg & 3;
  const int j0 = jc * 128;
  const int tid = threadIdx.x;
  __shared__ float cs[64][65];
  __shared__ float wo[64][128];
  const float* ch = ctx + ((size_t)b * 8 + h) * 4096;
#pragma unroll
  for (int it = 0; it < 16; ++it) {
    int flat = it * 256 + tid;  // 4096
    cs[flat >> 6][flat & 63] = ch[flat];
  }
#pragma unroll
  for (int it = 0; it < 32; ++it) {
    int flat = it * 256 + tid;  // 8192
    int e = flat >> 7, j = flat & 127;
    wo[e][j] = wout[(size_t)(h * 64 + e) * 512 + j0 + j];
  }
  __syncthreads();
  const int d = tid & 63;
  const int jg = (tid >> 6) * 32;
  for (int jj = 0; jj < 32; ++jj) {
    int j = jg + jj;
    float s = 0.0f;
#pragma unroll
    for (int e = 0; e < 64; ++e) s += cs[d][e] * wo[e][j];
    W2T[(size_t)b * 262144 + (size_t)(j0 + j) * 512 + h * 64 + d] = (__bf16)s;
  }
}

// ---------- K6: q feature-softmax (over c=64 per (t,h)) * C^-0.5
__global__ __launch_bounds__(256) void q_softmax(const __bf16* __restrict__ qkv,
                                                 __bf16* __restrict__ QS) {
  const int gid = blockIdx.x * 256 + threadIdx.x;
  const int g = gid >> 4;  // pair (t,h)
  const int l = gid & 15;
  const int t = g >> 3, h = g & 7;
  bf16x4 v = *(const bf16x4*)(qkv + (size_t)t * 1536 + h * 64 + l * 4);
  float f0 = (float)v[0], f1 = (float)v[1], f2 = (float)v[2], f3 = (float)v[3];
  float mx = fmaxf(fmaxf(f0, f1), fmaxf(f2, f3));
#pragma unroll
  for (int m = 1; m < 16; m <<= 1) mx = fmaxf(mx, __shfl_xor(mx, m));
  float e0 = __expf(f0 - mx), e1 = __expf(f1 - mx), e2 = __expf(f2 - mx),
        e3 = __expf(f3 - mx);
  float s = e0 + e1 + e2 + e3;
#pragma unroll
  for (int m = 1; m < 16; m <<= 1) s += __shfl_xor(s, m);
  float inv = 0.125f / s;  // * C^-0.5 (=1/8)
  bf16x4 o;
  o[0] = (__bf16)(e0 * inv); o[1] = (__bf16)(e1 * inv);
  o[2] = (__bf16)(e2 * inv); o[3] = (__bf16)(e3 * inv);
  *(bf16x4*)(QS + (size_t)t * 512 + h * 64 + l * 4) = o;
}

extern "C" void kernel_launch(void* const* d_in, const int* in_sizes, int n_in,
                              void* d_out, int out_size, void* d_ws, size_t ws_size,
                              hipStream_t stream) {
  const float* x = (const float*)d_in[0];
  const float* norm_w = (const float*)d_in[1];
  const float* w_qkv = (const float*)d_in[2];
  const float* mem_kv = (const float*)d_in[3];
  const float* w_out = (const float*)d_in[4];
  const float* b_out = (const float*)d_in[5];
  const float* onw = (const float*)d_in[6];

  char* ws = (char*)d_ws;
  __bf16* xn = (__bf16*)(ws + 0);              // 16 MB (region0)
  float* pctx = (float*)(ws + 0);              // 16 MB (region0, after GEMM1)
  __bf16* QS = (__bf16*)(ws + 0);              // 16 MB (region0, after ctx_final)
  __bf16* WqkvT = (__bf16*)(ws + 16777216);    // 1.5 MB
  __bf16* qkv = (__bf16*)(ws + 18350080);      // 48 MB
  float* pden = (float*)(ws + 68681728);       // 256 KB
  float* ctx = (float*)(ws + 68943872);        // 512 KB
  __bf16* W2T = (__bf16*)(ws + 69468160);      // 2 MB
  float* y = (float*)qkv;                      // reuse (qkv dead after q_softmax)

  wqkv_transpose<<<3072, 256, 0, stream>>>(w_qkv, WqkvT);
  rmsnorm_k<1><<<4096, 256, 0, stream>>>(x, norm_w, (void*)xn);
  gemm_bt128<0, 0><<<dim3(12, 128), 256, 0, stream>>>(xn, WqkvT, (void*)qkv,
                                                      nullptr, 16384, 1536, 512, 0);
  ctx_partial<<<1024, 256, 0, stream>>>(qkv, pctx, pden);
  ctx_final<<<32, 256, 0, stream>>>(pctx, pden, mem_kv, ctx);
  make_w2t<<<128, 256, 0, stream>>>(ctx, w_out, W2T);
  q_softmax<<<8192, 256, 0, stream>>>(qkv, QS);
  gemm_bt128<1, 1><<<dim3(4, 128), 256, 0, stream>>>(QS, W2T, (void*)y, b_out,
                                                     16384, 512, 512, 262144);
  rmsnorm_k<0><<<4096, 256, 0, stream>>>(y, onw, d_out);
}

// Round 3
// 134.873 us; speedup vs baseline: 1.3016x; 1.1489x over previous
//
#include <hip/hip_runtime.h>
#include <hip/hip_bf16.h>

// LinearAttention fused pipeline for MI355X (gfx950).
// Workspace layout (bytes), total 71,565,312 (~68 MB):
//   [0        , 16777216)  region0: xn bf16 [16384][512] -> pctx f32 [1024][64][64]
//   [16777216 , 18350080)  WqkvT bf16 [1536][512]
//   [18350080 , 51904512)  KV bf16 [16384][1024]  -> later y f32 [16384][512]
//   [51904512 , 68681728)  QS bf16 [16384][512]   (softmaxed q)
//   [68681728 , 68943872)  pden f32 [1024][64]
//   [68943872 , 69468160)  ctx  f32 [32][64][64]
//   [69468160 , 71565312)  W2T  bf16 [4][512][512]

typedef __attribute__((ext_vector_type(8))) __bf16 bf16x8;
typedef __attribute__((ext_vector_type(4))) __bf16 bf16x4;
typedef __attribute__((ext_vector_type(4))) float f32x4;

#define SQRT_DIM 22.627416997969522f

__device__ __forceinline__ void gload_lds16(const void* g, void* l) {
  __builtin_amdgcn_global_load_lds((__attribute__((address_space(1))) void*)g,
                                   (__attribute__((address_space(3))) void*)l, 16, 0, 0);
}

// ---------- K0: transpose w_qkv [512][1536] f32 -> WqkvT [1536][512] bf16
__global__ __launch_bounds__(256) void wqkv_transpose(const float* __restrict__ in,
                                                      __bf16* __restrict__ out) {
  int i = blockIdx.x * 256 + threadIdx.x;  // < 1536*512
  int n = i >> 9, k = i & 511;
  out[i] = (__bf16)in[k * 1536 + n];
}

// ---------- K1/K7: row L2-norm scale (x / max(||x||,1e-12) * w * sqrt(512))
template <int OUT_BF16>
__global__ __launch_bounds__(256) void rmsnorm_k(const float* __restrict__ x,
                                                 const float* __restrict__ w,
                                                 void* __restrict__ outv) {
  const int row = blockIdx.x * 4 + (threadIdx.x >> 6);
  const int lane = threadIdx.x & 63;
  const float4* xr = (const float4*)(x + (size_t)row * 512);
  float4 v0 = xr[lane], v1 = xr[lane + 64];
  float s = v0.x * v0.x + v0.y * v0.y + v0.z * v0.z + v0.w * v0.w +
            v1.x * v1.x + v1.y * v1.y + v1.z * v1.z + v1.w * v1.w;
#pragma unroll
  for (int m = 1; m < 64; m <<= 1) s += __shfl_xor(s, m);
  const float sc = SQRT_DIM / fmaxf(sqrtf(s), 1e-12f);
  const float4* wr4 = (const float4*)w;
  float4 w0 = wr4[lane], w1 = wr4[lane + 64];
  float o0 = v0.x * sc * w0.x, o1 = v0.y * sc * w0.y, o2 = v0.z * sc * w0.z,
        o3 = v0.w * sc * w0.w;
  float o4 = v1.x * sc * w1.x, o5 = v1.y * sc * w1.y, o6 = v1.z * sc * w1.z,
        o7 = v1.w * sc * w1.w;
  if (OUT_BF16) {
    __bf16* out = (__bf16*)outv + (size_t)row * 512;
    bf16x4 a, b2;
    a[0] = (__bf16)o0; a[1] = (__bf16)o1; a[2] = (__bf16)o2; a[3] = (__bf16)o3;
    b2[0] = (__bf16)o4; b2[1] = (__bf16)o5; b2[2] = (__bf16)o6; b2[3] = (__bf16)o7;
    *(bf16x4*)(out + lane * 4) = a;
    *(bf16x4*)(out + 256 + lane * 4) = b2;
  } else {
    float* out = (float*)outv + (size_t)row * 512;
    ((float4*)out)[lane] = make_float4(o0, o1, o2, o3);
    ((float4*)out)[lane + 64] = make_float4(o4, o5, o6, o7);
  }
}

// ---------- 2-phase double-buffered GEMM, BM=256 BN=128 BK=64, 512 thr (8 waves, 4M x 2N)
// LDS st-swizzle: LDS[row][chunk] holds G[row][chunk ^ (row&7)] (16B chunks); readers
// apply the same XOR. global_load_lds dest stays linear (rule #21).
// MODE 0: A=xn[16384][512], BT=WqkvT[1536][512]. Cols<512: fused q-feature-softmax -> QS.
//         Cols>=512: k,v -> KV[16384][1024].
// MODE 1: A=QS, BT=W2T (per-batch 512x512), Y=f32 out + bias.
template <int MODE, int NX>
__global__ __launch_bounds__(512) void gemm2ph(const __bf16* __restrict__ A,
                                               const __bf16* __restrict__ BT,
                                               __bf16* __restrict__ QS,
                                               __bf16* __restrict__ KV,
                                               float* __restrict__ Y,
                                               const float* __restrict__ bias) {
  __shared__ __bf16 As[2][256 * 64];
  __shared__ __bf16 Bs[2][128 * 64];
  const int K = 512;
  const int tid = threadIdx.x;
  const int lane = tid & 63;
  const int wave = tid >> 6;
  const int wr = (wave >> 1) * 64;  // 4 M-waves
  const int wc = (wave & 1) * 64;   // 2 N-waves
  const int l15 = lane & 15, lg = lane >> 4;
  // XCD-chunked swizzle (grid size multiple of 8)
  const int cpx = gridDim.x >> 3;
  const int fid = blockIdx.x;
  const int tile = (fid & 7) * cpx + (fid >> 3);
  const int my = tile / NX;
  const int m0 = my * 256;
  const int n0 = (tile - my * NX) * 128;
  const __bf16* bt = (MODE == 1) ? BT + (size_t)(my >> 4) * 262144 : BT;

  f32x4 acc[4][4] = {};

  auto stage = [&](int buf, int k0) {
#pragma unroll
    for (int it = 0; it < 4; ++it) {
      int flat = it * 512 + tid;
      int row = flat >> 3;
      int cb = ((flat & 7) ^ (row & 7)) * 16;  // pre-swizzled source chunk
      gload_lds16((const char*)(A + (size_t)(m0 + row) * K + k0) + cb,
                  (char*)(&As[buf][0]) + flat * 16);
    }
#pragma unroll
    for (int it = 0; it < 2; ++it) {
      int flat = it * 512 + tid;
      int row = flat >> 3;
      int cb = ((flat & 7) ^ (row & 7)) * 16;
      gload_lds16((const char*)(bt + (size_t)(n0 + row) * K + k0) + cb,
                  (char*)(&Bs[buf][0]) + flat * 16);
    }
  };
  auto compute = [&](int buf) {
#pragma unroll
    for (int kk = 0; kk < 2; ++kk) {
      bf16x8 af[4], bfr[4];
      const int sw = (kk * 4 + lg) ^ (l15 & 7);  // swizzled 16B chunk for this lane
#pragma unroll
      for (int i = 0; i < 4; ++i) {
        af[i] = *(const bf16x8*)(&As[buf][(wr + i * 16 + l15) * 64 + sw * 8]);
        bfr[i] = *(const bf16x8*)(&Bs[buf][(wc + i * 16 + l15) * 64 + sw * 8]);
      }
      __builtin_amdgcn_s_setprio(1);
#pragma unroll
      for (int mi = 0; mi < 4; ++mi)
#pragma unroll
        for (int ni = 0; ni < 4; ++ni)
          acc[mi][ni] = __builtin_amdgcn_mfma_f32_16x16x32_bf16(
              af[mi], bfr[ni], acc[mi][ni], 0, 0, 0);
      __builtin_amdgcn_s_setprio(0);
    }
  };

  stage(0, 0);
  __syncthreads();
  int cur = 0;
  for (int t = 0; t < 7; ++t) {
    stage(cur ^ 1, (t + 1) * 64);  // prefetch next K-tile into other buffer
    compute(cur);                  // MFMA on current (hides prefetch latency)
    __syncthreads();               // drains vmcnt(0): next buffer ready
    cur ^= 1;
  }
  compute(cur);

  if (MODE == 0) {
    if (n0 < 512) {
      // fused q feature-softmax: each wave owns exactly one head's 64 cols per row
#pragma unroll
      for (int mi = 0; mi < 4; ++mi)
#pragma unroll
        for (int r = 0; r < 4; ++r) {
          float v0_ = acc[mi][0][r], v1_ = acc[mi][1][r], v2_ = acc[mi][2][r],
                v3_ = acc[mi][3][r];
          float mx = fmaxf(fmaxf(v0_, v1_), fmaxf(v2_, v3_));
#pragma unroll
          for (int m = 1; m < 16; m <<= 1) mx = fmaxf(mx, __shfl_xor(mx, m));
          float e0 = __expf(v0_ - mx), e1 = __expf(v1_ - mx),
                e2 = __expf(v2_ - mx), e3 = __expf(v3_ - mx);
          float s = e0 + e1 + e2 + e3;
#pragma unroll
          for (int m = 1; m < 16; m <<= 1) s += __shfl_xor(s, m);
          float inv = 0.125f / s;  // * C^-0.5
          size_t rwb = (size_t)(m0 + wr + mi * 16 + lg * 4 + r) * 512 + n0 + wc;
          QS[rwb + l15] = (__bf16)(e0 * inv);
          QS[rwb + 16 + l15] = (__bf16)(e1 * inv);
          QS[rwb + 32 + l15] = (__bf16)(e2 * inv);
          QS[rwb + 48 + l15] = (__bf16)(e3 * inv);
        }
    } else {
#pragma unroll
      for (int mi = 0; mi < 4; ++mi)
#pragma unroll
        for (int ni = 0; ni < 4; ++ni) {
          int col = (n0 - 512) + wc + ni * 16 + l15;
#pragma unroll
          for (int r = 0; r < 4; ++r) {
            int rw = m0 + wr + mi * 16 + lg * 4 + r;
            KV[(size_t)rw * 1024 + col] = (__bf16)acc[mi][ni][r];
          }
        }
    }
  } else {
#pragma unroll
    for (int mi = 0; mi < 4; ++mi)
#pragma unroll
      for (int ni = 0; ni < 4; ++ni) {
        int col = n0 + wc + ni * 16 + l15;
        float bv = bias[col];
#pragma unroll
        for (int r = 0; r < 4; ++r) {
          int rw = m0 + wr + mi * 16 + lg * 4 + r;
          Y[(size_t)rw * 512 + col] = acc[mi][ni][r] + bv;
        }
      }
  }
}

// ---------- K3: partial context: pctx[wg] = sum_tokens exp(k[d])*v[e]; pden = sum exp(k[d])
// 1024 blocks = bh(32) x chunk(32), 128 tokens per chunk. KV layout [16384][1024] (k|v).
__global__ __launch_bounds__(256) void ctx_partial(const __bf16* __restrict__ kv,
                                                   float* __restrict__ pctx,
                                                   float* __restrict__ pden) {
  const int wg = blockIdx.x;  // bh*32 + chunk
  const int bh = wg >> 5, chunk = wg & 31;
  const int b = bh >> 3, h = bh & 7;
  const int tid = threadIdx.x;
  __shared__ float ek[16][64];
  __shared__ float vv[16][64];
  float acc[4][4] = {};
  float dsum = 0.0f;
  const int td = (tid >> 4) * 4, te = (tid & 15) * 4;
  const int tokc = tid >> 4, rr = tid & 15;
  for (int t0 = 0; t0 < 128; t0 += 16) {
    __syncthreads();
    {
      int tok = b * 4096 + chunk * 128 + t0 + tokc;
      const __bf16* base = kv + (size_t)tok * 1024 + h * 64;  // k block
      if (rr < 8) {
        bf16x8 kx = *(const bf16x8*)(base + rr * 8);
#pragma unroll
        for (int j = 0; j < 8; ++j) ek[tokc][rr * 8 + j] = __expf((float)kx[j]);
      } else {
        bf16x8 vx = *(const bf16x8*)(base + 512 + (rr - 8) * 8);  // v block
#pragma unroll
        for (int j = 0; j < 8; ++j) vv[tokc][(rr - 8) * 8 + j] = (float)vx[j];
      }
    }
    __syncthreads();
#pragma unroll
    for (int t = 0; t < 16; ++t) {
      float4 a4 = *(const float4*)&ek[t][td];
      float4 b4 = *(const float4*)&vv[t][te];
      float aa[4] = {a4.x, a4.y, a4.z, a4.w};
      float bb[4] = {b4.x, b4.y, b4.z, b4.w};
#pragma unroll
      for (int i = 0; i < 4; ++i)
#pragma unroll
        for (int j = 0; j < 4; ++j) acc[i][j] += aa[i] * bb[j];
    }
    if (tid < 64) {
#pragma unroll
      for (int t = 0; t < 16; ++t) dsum += ek[t][tid];
    }
  }
  float* op = pctx + (size_t)wg * 4096;
#pragma unroll
  for (int i = 0; i < 4; ++i)
#pragma unroll
    for (int j = 0; j < 4; ++j) op[(td + i) * 64 + te + j] = acc[i][j];
  if (tid < 64) pden[wg * 64 + tid] = dsum;
}

// ---------- K4: finalize ctx with memory-KV and softmax denominator (32 chunks)
__global__ __launch_bounds__(256) void ctx_final(const float* __restrict__ pctx,
                                                 const float* __restrict__ pden,
                                                 const float* __restrict__ memkv,
                                                 float* __restrict__ ctx) {
  const int bh = blockIdx.x;  // 0..31
  const int h = bh & 7;
  const int tid = threadIdx.x;
  __shared__ float emk[64][8], mvl[64][8], den[64];
  if (tid < 64) {
    float d = 0.0f;
#pragma unroll
    for (int m = 0; m < 8; ++m) {
      float e = __expf(memkv[(size_t)h * 512 + tid * 8 + m]);
      emk[tid][m] = e;
      d += e;
      mvl[tid][m] = memkv[4096 + (size_t)h * 512 + tid * 8 + m];
    }
#pragma unroll
    for (int c = 0; c < 32; ++c) d += pden[((size_t)bh * 32 + c) * 64 + tid];
    den[tid] = d;
  }
  __syncthreads();
  const int td = (tid >> 4) * 4, te = (tid & 15) * 4;
#pragma unroll
  for (int i = 0; i < 4; ++i) {
    int dd = td + i;
    float invd = 1.0f / den[dd];
#pragma unroll
    for (int j = 0; j < 4; ++j) {
      int e = te + j;
      float s = 0.0f;
#pragma unroll
      for (int m = 0; m < 8; ++m) s += emk[dd][m] * mvl[e][m];
#pragma unroll
      for (int c = 0; c < 32; ++c)
        s += pctx[((size_t)bh * 32 + c) * 4096 + dd * 64 + e];
      ctx[(size_t)bh * 4096 + dd * 64 + e] = s * invd;
    }
  }
}

// ---------- K5: fold ctx into w_out: W2T[b][j][h*64+d] = sum_e ctx[b,h,d,e]*w_out[h*64+e][j]
__global__ __launch_bounds__(256) void make_w2t(const float* __restrict__ ctx,
                                                const float* __restrict__ wout,
                                                __bf16* __restrict__ W2T) {
  const int wg = blockIdx.x;  // b*32 + h*4 + jc
  const int b = wg >> 5, h = (wg >> 2) & 7, jc = wg & 3;
  const int j0 = jc * 128;
  const int tid = threadIdx.x;
  __shared__ float cs[64][65];
  __shared__ float wo[64][128];
  const float* ch = ctx + ((size_t)b * 8 + h) * 4096;
#pragma unroll
  for (int it = 0; it < 16; ++it) {
    int flat = it * 256 + tid;
    cs[flat >> 6][flat & 63] = ch[flat];
  }
#pragma unroll
  for (int it = 0; it < 32; ++it) {
    int flat = it * 256 + tid;
    int e = flat >> 7, j = flat & 127;
    wo[e][j] = wout[(size_t)(h * 64 + e) * 512 + j0 + j];
  }
  __syncthreads();
  const int d = tid & 63;
  const int jg = (tid >> 6) * 32;
  for (int jj = 0; jj < 32; ++jj) {
    int j = jg + jj;
    float s = 0.0f;
#pragma unroll
    for (int e = 0; e < 64; ++e) s += cs[d][e] * wo[e][j];
    W2T[(size_t)b * 262144 + (size_t)(j0 + j) * 512 + h * 64 + d] = (__bf16)s;
  }
}

extern "C" void kernel_launch(void* const* d_in, const int* in_sizes, int n_in,
                              void* d_out, int out_size, void* d_ws, size_t ws_size,
                              hipStream_t stream) {
  const float* x = (const float*)d_in[0];
  const float* norm_w = (const float*)d_in[1];
  const float* w_qkv = (const float*)d_in[2];
  const float* mem_kv = (const float*)d_in[3];
  const float* w_out = (const float*)d_in[4];
  const float* b_out = (const float*)d_in[5];
  const float* onw = (const float*)d_in[6];

  char* ws = (char*)d_ws;
  __bf16* xn = (__bf16*)(ws + 0);            // 16 MB (region0)
  float* pctx = (float*)(ws + 0);            // 16 MB (region0, xn dead after GEMM1)
  __bf16* WqkvT = (__bf16*)(ws + 16777216);  // 1.5 MB
  __bf16* KV = (__bf16*)(ws + 18350080);     // 32 MB
  float* y = (float*)KV;                     // reuse (KV dead after ctx_partial)
  __bf16* QS = (__bf16*)(ws + 51904512);     // 16 MB
  float* pden = (float*)(ws + 68681728);     // 256 KB
  float* ctx = (float*)(ws + 68943872);      // 512 KB
  __bf16* W2T = (__bf16*)(ws + 69468160);    // 2 MB

  wqkv_transpose<<<3072, 256, 0, stream>>>(w_qkv, WqkvT);
  rmsnorm_k<1><<<4096, 256, 0, stream>>>(x, norm_w, (void*)xn);
  gemm2ph<0, 12><<<768, 512, 0, stream>>>(xn, WqkvT, QS, KV, nullptr, nullptr);
  ctx_partial<<<1024, 256, 0, stream>>>(KV, pctx, pden);
  ctx_final<<<32, 256, 0, stream>>>(pctx, pden, mem_kv, ctx);
  make_w2t<<<128, 256, 0, stream>>>(ctx, w_out, W2T);
  gemm2ph<1, 4><<<256, 512, 0, stream>>>(QS, W2T, nullptr, nullptr, y, b_out);
  rmsnorm_k<0><<<4096, 256, 0, stream>>>(y, onw, d_out);
}

// Round 4
// 132.433 us; speedup vs baseline: 1.3256x; 1.0184x over previous
//
#include <hip/hip_runtime.h>
#include <hip/hip_bf16.h>

// LinearAttention fused pipeline for MI355X (gfx950).
// Workspace layout (bytes), total 71,565,312 (~68 MB):
//   [0        , 16777216)  region0: xn bf16 [16384][512] -> pctx f32 [1024][64][64]
//   [16777216 , 18350080)  WqkvT bf16 [1536][512]
//   [18350080 , 51904512)  KV bf16 [16384][1024]  -> later y f32 [16384][512]
//   [51904512 , 68681728)  QS bf16 [16384][512]   (softmaxed q)
//   [68681728 , 68943872)  pden f32 [1024][64]
//   [68943872 , 69468160)  ctx  f32 [32][64][64]
//   [69468160 , 71565312)  W2T  bf16 [4][512][512]

typedef __attribute__((ext_vector_type(8))) __bf16 bf16x8;
typedef __attribute__((ext_vector_type(4))) __bf16 bf16x4;
typedef __attribute__((ext_vector_type(4))) float f32x4;

#define SQRT_DIM 22.627416997969522f

__device__ __forceinline__ void gload_lds16(const void* g, void* l) {
  __builtin_amdgcn_global_load_lds((__attribute__((address_space(1))) void*)g,
                                   (__attribute__((address_space(3))) void*)l, 16, 0, 0);
}

// ---------- K0: tiled transpose w_qkv [512][1536] f32 -> WqkvT [1536][512] bf16
__global__ __launch_bounds__(256) void wqkv_transpose(const float* __restrict__ in,
                                                      __bf16* __restrict__ out) {
  const int n0 = blockIdx.x * 64, k0 = blockIdx.y * 64;
  __shared__ float t[64][65];
  const int tid = threadIdx.x;
  const int r = tid >> 4, c4 = (tid & 15) * 4;
#pragma unroll
  for (int p = 0; p < 4; ++p) {
    float4 v = *(const float4*)(in + (size_t)(k0 + p * 16 + r) * 1536 + n0 + c4);
    t[p * 16 + r][c4 + 0] = v.x;
    t[p * 16 + r][c4 + 1] = v.y;
    t[p * 16 + r][c4 + 2] = v.z;
    t[p * 16 + r][c4 + 3] = v.w;
  }
  __syncthreads();
#pragma unroll
  for (int p = 0; p < 4; ++p) {
    int c = p * 256 + tid;
    int rn = c >> 4, cc = (c & 15) * 4;
    bf16x4 o;
#pragma unroll
    for (int j = 0; j < 4; ++j) o[j] = (__bf16)t[cc + j][rn];
    *(bf16x4*)(out + (size_t)(n0 + rn) * 512 + k0 + cc) = o;
  }
}

// ---------- K1/K7: row L2-norm scale (x / max(||x||,1e-12) * w * sqrt(512))
template <int OUT_BF16>
__global__ __launch_bounds__(256) void rmsnorm_k(const float* __restrict__ x,
                                                 const float* __restrict__ w,
                                                 void* __restrict__ outv) {
  const int row = blockIdx.x * 4 + (threadIdx.x >> 6);
  const int lane = threadIdx.x & 63;
  const float4* xr = (const float4*)(x + (size_t)row * 512);
  float4 v0 = xr[lane], v1 = xr[lane + 64];
  float s = v0.x * v0.x + v0.y * v0.y + v0.z * v0.z + v0.w * v0.w +
            v1.x * v1.x + v1.y * v1.y + v1.z * v1.z + v1.w * v1.w;
#pragma unroll
  for (int m = 1; m < 64; m <<= 1) s += __shfl_xor(s, m);
  const float sc = SQRT_DIM / fmaxf(sqrtf(s), 1e-12f);
  const float4* wr4 = (const float4*)w;
  float4 w0 = wr4[lane], w1 = wr4[lane + 64];
  float o0 = v0.x * sc * w0.x, o1 = v0.y * sc * w0.y, o2 = v0.z * sc * w0.z,
        o3 = v0.w * sc * w0.w;
  float o4 = v1.x * sc * w1.x, o5 = v1.y * sc * w1.y, o6 = v1.z * sc * w1.z,
        o7 = v1.w * sc * w1.w;
  if (OUT_BF16) {
    __bf16* out = (__bf16*)outv + (size_t)row * 512;
    bf16x4 a, b2;
    a[0] = (__bf16)o0; a[1] = (__bf16)o1; a[2] = (__bf16)o2; a[3] = (__bf16)o3;
    b2[0] = (__bf16)o4; b2[1] = (__bf16)o5; b2[2] = (__bf16)o6; b2[3] = (__bf16)o7;
    *(bf16x4*)(out + lane * 4) = a;
    *(bf16x4*)(out + 256 + lane * 4) = b2;
  } else {
    float* out = (float*)outv + (size_t)row * 512;
    ((float4*)out)[lane] = make_float4(o0, o1, o2, o3);
    ((float4*)out)[lane + 64] = make_float4(o4, o5, o6, o7);
  }
}

// ---------- Counted-vmcnt pipelined GEMM (T2+T3+T4+T5), BM=256 BN=128 BK=64,
// 512 thr (8 waves, 4M x 2N), 2-K-tile-deep prefetch, raw barriers.
// Per K-tile: ds_read 16 frags -> lgkmcnt(0)+barrier (buf consumed) ->
// stage(kt+2) into freed buf -> 32 MFMA (setprio) -> vmcnt(6)+barrier (next ready).
// MODE 0: A=xn[16384][512], BT=WqkvT[1536][512]. Cols<512: fused q-softmax -> QS.
//         Cols>=512: k,v -> KV[16384][1024].
// MODE 1: A=QS, BT=W2T (per-batch 512x512), Y=f32 + bias.
template <int MODE, int NX>
__global__ __launch_bounds__(512) void gemm8p(const __bf16* __restrict__ A,
                                              const __bf16* __restrict__ BT,
                                              __bf16* __restrict__ QS,
                                              __bf16* __restrict__ KV,
                                              float* __restrict__ Y,
                                              const float* __restrict__ bias) {
  __shared__ __bf16 As[2][256 * 64];
  __shared__ __bf16 Bs[2][128 * 64];
  const int K = 512;
  const int NT = 8;  // K / 64
  const int tid = threadIdx.x;
  const int lane = tid & 63;
  const int wave = tid >> 6;
  const int wr = (wave >> 1) * 64;  // 4 M-waves
  const int wc = (wave & 1) * 64;   // 2 N-waves
  const int l15 = lane & 15, lg = lane >> 4;
  // XCD-chunked swizzle (grid size multiple of 8)
  const int cpx = gridDim.x >> 3;
  const int fid = blockIdx.x;
  const int tile = (fid & 7) * cpx + (fid >> 3);
  const int my = tile / NX;
  const int m0 = my * 256;
  const int n0 = (tile - my * NX) * 128;
  const __bf16* bt = (MODE == 1) ? BT + (size_t)(my >> 4) * 262144 : BT;

  f32x4 acc[4][4] = {};

  auto stage = [&](int buf, int k0) {
#pragma unroll
    for (int it = 0; it < 4; ++it) {
      int flat = it * 512 + tid;
      int row = flat >> 3;
      int cb = ((flat & 7) ^ (row & 7)) * 16;  // pre-swizzled source chunk (T2)
      gload_lds16((const char*)(A + (size_t)(m0 + row) * K + k0) + cb,
                  (char*)(&As[buf][0]) + flat * 16);
    }
#pragma unroll
    for (int it = 0; it < 2; ++it) {
      int flat = it * 512 + tid;
      int row = flat >> 3;
      int cb = ((flat & 7) ^ (row & 7)) * 16;
      gload_lds16((const char*)(bt + (size_t)(n0 + row) * K + k0) + cb,
                  (char*)(&Bs[buf][0]) + flat * 16);
    }
  };

  // Prologue: stage K-tiles 0 and 1; wait tile-0 done (keep tile-1 in flight).
  stage(0, 0);
  stage(1, 64);
  asm volatile("s_waitcnt vmcnt(6)" ::: "memory");
  __builtin_amdgcn_s_barrier();

  for (int kt = 0; kt < NT; ++kt) {
    const int cur = kt & 1;
    bf16x8 a0[4], b0[4], a1[4], b1[4];
    const int sw0 = lg ^ (l15 & 7);        // swizzled chunk, kk=0
    const int sw1 = (4 + lg) ^ (l15 & 7);  // swizzled chunk, kk=1
#pragma unroll
    for (int i = 0; i < 4; ++i) {
      a0[i] = *(const bf16x8*)(&As[cur][(wr + i * 16 + l15) * 64 + sw0 * 8]);
      b0[i] = *(const bf16x8*)(&Bs[cur][(wc + i * 16 + l15) * 64 + sw0 * 8]);
      a1[i] = *(const bf16x8*)(&As[cur][(wr + i * 16 + l15) * 64 + sw1 * 8]);
      b1[i] = *(const bf16x8*)(&Bs[cur][(wc + i * 16 + l15) * 64 + sw1 * 8]);
    }
    asm volatile("s_waitcnt lgkmcnt(0)" ::: "memory");
    __builtin_amdgcn_sched_barrier(0);
    __builtin_amdgcn_s_barrier();  // buf[cur] fully consumed by all waves
    if (kt + 2 < NT) stage(cur, (kt + 2) * 64);  // overwrite freed buffer
    __builtin_amdgcn_s_setprio(1);
#pragma unroll
    for (int mi = 0; mi < 4; ++mi)
#pragma unroll
      for (int ni = 0; ni < 4; ++ni)
        acc[mi][ni] = __builtin_amdgcn_mfma_f32_16x16x32_bf16(a0[mi], b0[ni],
                                                              acc[mi][ni], 0, 0, 0);
    __builtin_amdgcn_s_setprio(0);
    __builtin_amdgcn_s_setprio(1);
#pragma unroll
    for (int mi = 0; mi < 4; ++mi)
#pragma unroll
      for (int ni = 0; ni < 4; ++ni)
        acc[mi][ni] = __builtin_amdgcn_mfma_f32_16x16x32_bf16(a1[mi], b1[ni],
                                                              acc[mi][ni], 0, 0, 0);
    __builtin_amdgcn_s_setprio(0);
    if (kt < NT - 1) {
      if (kt + 2 < NT)
        asm volatile("s_waitcnt vmcnt(6)" ::: "memory");  // next tile done, keep 6
      else
        asm volatile("s_waitcnt vmcnt(0)" ::: "memory");  // tail drain
      __builtin_amdgcn_s_barrier();  // buf[cur^1] ready
    }
  }

  if (MODE == 0) {
    if (n0 < 512) {
      // fused q feature-softmax: each wave owns exactly one head's 64 cols per row
#pragma unroll
      for (int mi = 0; mi < 4; ++mi)
#pragma unroll
        for (int r = 0; r < 4; ++r) {
          float v0_ = acc[mi][0][r], v1_ = acc[mi][1][r], v2_ = acc[mi][2][r],
                v3_ = acc[mi][3][r];
          float mx = fmaxf(fmaxf(v0_, v1_), fmaxf(v2_, v3_));
#pragma unroll
          for (int m = 1; m < 16; m <<= 1) mx = fmaxf(mx, __shfl_xor(mx, m));
          float e0 = __expf(v0_ - mx), e1 = __expf(v1_ - mx),
                e2 = __expf(v2_ - mx), e3 = __expf(v3_ - mx);
          float s = e0 + e1 + e2 + e3;
#pragma unroll
          for (int m = 1; m < 16; m <<= 1) s += __shfl_xor(s, m);
          float inv = 0.125f / s;  // * C^-0.5
          size_t rwb = (size_t)(m0 + wr + mi * 16 + lg * 4 + r) * 512 + n0 + wc;
          QS[rwb + l15] = (__bf16)(e0 * inv);
          QS[rwb + 16 + l15] = (__bf16)(e1 * inv);
          QS[rwb + 32 + l15] = (__bf16)(e2 * inv);
          QS[rwb + 48 + l15] = (__bf16)(e3 * inv);
        }
    } else {
#pragma unroll
      for (int mi = 0; mi < 4; ++mi)
#pragma unroll
        for (int ni = 0; ni < 4; ++ni) {
          int col = (n0 - 512) + wc + ni * 16 + l15;
#pragma unroll
          for (int r = 0; r < 4; ++r) {
            int rw = m0 + wr + mi * 16 + lg * 4 + r;
            KV[(size_t)rw * 1024 + col] = (__bf16)acc[mi][ni][r];
          }
        }
    }
  } else {
#pragma unroll
    for (int mi = 0; mi < 4; ++mi)
#pragma unroll
      for (int ni = 0; ni < 4; ++ni) {
        int col = n0 + wc + ni * 16 + l15;
        float bv = bias[col];
#pragma unroll
        for (int r = 0; r < 4; ++r) {
          int rw = m0 + wr + mi * 16 + lg * 4 + r;
          Y[(size_t)rw * 512 + col] = acc[mi][ni][r] + bv;
        }
      }
  }
}

// ---------- K3: partial context: pctx[wg] = sum_tokens exp(k[d])*v[e]; pden = sum exp(k[d])
// 1024 blocks = bh(32) x chunk(32), 128 tokens per chunk. KV layout [16384][1024] (k|v).
__global__ __launch_bounds__(256) void ctx_partial(const __bf16* __restrict__ kv,
                                                   float* __restrict__ pctx,
                                                   float* __restrict__ pden) {
  const int wg = blockIdx.x;  // bh*32 + chunk
  const int bh = wg >> 5, chunk = wg & 31;
  const int b = bh >> 3, h = bh & 7;
  const int tid = threadIdx.x;
  __shared__ float ek[16][64];
  __shared__ float vv[16][64];
  float acc[4][4] = {};
  float dsum = 0.0f;
  const int td = (tid >> 4) * 4, te = (tid & 15) * 4;
  const int tokc = tid >> 4, rr = tid & 15;
  for (int t0 = 0; t0 < 128; t0 += 16) {
    __syncthreads();
    {
      int tok = b * 4096 + chunk * 128 + t0 + tokc;
      const __bf16* base = kv + (size_t)tok * 1024 + h * 64;  // k block
      if (rr < 8) {
        bf16x8 kx = *(const bf16x8*)(base + rr * 8);
#pragma unroll
        for (int j = 0; j < 8; ++j) ek[tokc][rr * 8 + j] = __expf((float)kx[j]);
      } else {
        bf16x8 vx = *(const bf16x8*)(base + 512 + (rr - 8) * 8);  // v block
#pragma unroll
        for (int j = 0; j < 8; ++j) vv[tokc][(rr - 8) * 8 + j] = (float)vx[j];
      }
    }
    __syncthreads();
#pragma unroll
    for (int t = 0; t < 16; ++t) {
      float4 a4 = *(const float4*)&ek[t][td];
      float4 b4 = *(const float4*)&vv[t][te];
      float aa[4] = {a4.x, a4.y, a4.z, a4.w};
      float bb[4] = {b4.x, b4.y, b4.z, b4.w};
#pragma unroll
      for (int i = 0; i < 4; ++i)
#pragma unroll
        for (int j = 0; j < 4; ++j) acc[i][j] += aa[i] * bb[j];
    }
    if (tid < 64) {
#pragma unroll
      for (int t = 0; t < 16; ++t) dsum += ek[t][tid];
    }
  }
  float* op = pctx + (size_t)wg * 4096;
#pragma unroll
  for (int i = 0; i < 4; ++i)
#pragma unroll
    for (int j = 0; j < 4; ++j) op[(td + i) * 64 + te + j] = acc[i][j];
  if (tid < 64) pden[wg * 64 + tid] = dsum;
}

// ---------- K4: finalize ctx with memory-KV and softmax denominator (32 chunks)
__global__ __launch_bounds__(256) void ctx_final(const float* __restrict__ pctx,
                                                 const float* __restrict__ pden,
                                                 const float* __restrict__ memkv,
                                                 float* __restrict__ ctx) {
  const int bh = blockIdx.x;  // 0..31
  const int h = bh & 7;
  const int tid = threadIdx.x;
  __shared__ float emk[64][8], mvl[64][8], den[64];
  if (tid < 64) {
    float d = 0.0f;
#pragma unroll
    for (int m = 0; m < 8; ++m) {
      float e = __expf(memkv[(size_t)h * 512 + tid * 8 + m]);
      emk[tid][m] = e;
      d += e;
      mvl[tid][m] = memkv[4096 + (size_t)h * 512 + tid * 8 + m];
    }
#pragma unroll
    for (int c = 0; c < 32; ++c) d += pden[((size_t)bh * 32 + c) * 64 + tid];
    den[tid] = d;
  }
  __syncthreads();
  const int td = (tid >> 4) * 4, te = (tid & 15) * 4;
#pragma unroll
  for (int i = 0; i < 4; ++i) {
    int dd = td + i;
    float invd = 1.0f / den[dd];
#pragma unroll
    for (int j = 0; j < 4; ++j) {
      int e = te + j;
      float s = 0.0f;
#pragma unroll
      for (int m = 0; m < 8; ++m) s += emk[dd][m] * mvl[e][m];
#pragma unroll
      for (int c = 0; c < 32; ++c)
        s += pctx[((size_t)bh * 32 + c) * 4096 + dd * 64 + e];
      ctx[(size_t)bh * 4096 + dd * 64 + e] = s * invd;
    }
  }
}

// ---------- K5: fold ctx into w_out: W2T[b][j][h*64+d] = sum_e ctx[b,h,d,e]*w_out[h*64+e][j]
__global__ __launch_bounds__(256) void make_w2t(const float* __restrict__ ctx,
                                                const float* __restrict__ wout,
                                                __bf16* __restrict__ W2T) {
  const int wg = blockIdx.x;  // b*32 + h*4 + jc
  const int b = wg >> 5, h = (wg >> 2) & 7, jc = wg & 3;
  const int j0 = jc * 128;
  const int tid = threadIdx.x;
  __shared__ float cs[64][65];
  __shared__ float wo[64][128];
  const float* ch = ctx + ((size_t)b * 8 + h) * 4096;
#pragma unroll
  for (int it = 0; it < 16; ++it) {
    int flat = it * 256 + tid;
    cs[flat >> 6][flat & 63] = ch[flat];
  }
#pragma unroll
  for (int it = 0; it < 32; ++it) {
    int flat = it * 256 + tid;
    int e = flat >> 7, j = flat & 127;
    wo[e][j] = wout[(size_t)(h * 64 + e) * 512 + j0 + j];
  }
  __syncthreads();
  const int d = tid & 63;
  const int jg = (tid >> 6) * 32;
  for (int jj = 0; jj < 32; ++jj) {
    int j = jg + jj;
    float s = 0.0f;
#pragma unroll
    for (int e = 0; e < 64; ++e) s += cs[d][e] * wo[e][j];
    W2T[(size_t)b * 262144 + (size_t)(j0 + j) * 512 + h * 64 + d] = (__bf16)s;
  }
}

extern "C" void kernel_launch(void* const* d_in, const int* in_sizes, int n_in,
                              void* d_out, int out_size, void* d_ws, size_t ws_size,
                              hipStream_t stream) {
  const float* x = (const float*)d_in[0];
  const float* norm_w = (const float*)d_in[1];
  const float* w_qkv = (const float*)d_in[2];
  const float* mem_kv = (const float*)d_in[3];
  const float* w_out = (const float*)d_in[4];
  const float* b_out = (const float*)d_in[5];
  const float* onw = (const float*)d_in[6];

  char* ws = (char*)d_ws;
  __bf16* xn = (__bf16*)(ws + 0);            // 16 MB (region0)
  float* pctx = (float*)(ws + 0);            // 16 MB (region0, xn dead after GEMM1)
  __bf16* WqkvT = (__bf16*)(ws + 16777216);  // 1.5 MB
  __bf16* KV = (__bf16*)(ws + 18350080);     // 32 MB
  float* y = (float*)KV;                     // reuse (KV dead after ctx_partial)
  __bf16* QS = (__bf16*)(ws + 51904512);     // 16 MB
  float* pden = (float*)(ws + 68681728);     // 256 KB
  float* ctx = (float*)(ws + 68943872);      // 512 KB
  __bf16* W2T = (__bf16*)(ws + 69468160);    // 2 MB

  wqkv_transpose<<<dim3(24, 8), 256, 0, stream>>>(w_qkv, WqkvT);
  rmsnorm_k<1><<<4096, 256, 0, stream>>>(x, norm_w, (void*)xn);
  gemm8p<0, 12><<<768, 512, 0, stream>>>(xn, WqkvT, QS, KV, nullptr, nullptr);
  ctx_partial<<<1024, 256, 0, stream>>>(KV, pctx, pden);
  ctx_final<<<32, 256, 0, stream>>>(pctx, pden, mem_kv, ctx);
  make_w2t<<<128, 256, 0, stream>>>(ctx, w_out, W2T);
  gemm8p<1, 4><<<256, 512, 0, stream>>>(QS, W2T, nullptr, nullptr, y, b_out);
  rmsnorm_k<0><<<4096, 256, 0, stream>>>(y, onw, d_out);
}

// Round 5
// 126.369 us; speedup vs baseline: 1.3892x; 1.0480x over previous
//
#include <hip/hip_runtime.h>
#include <hip/hip_bf16.h>

// LinearAttention fused pipeline for MI355X (gfx950).
// Workspace layout (bytes), total 71,565,312 (~68 MB):
//   [0        , 16777216)  region0: xn bf16 [16384][512] -> pctx f32 [1024][64][64]
//   [16777216 , 18350080)  WqkvT bf16 [1536][512]
//   [18350080 , 51904512)  KV bf16 [16384][1024]
//   [51904512 , 68681728)  QS bf16 [16384][512]   (softmaxed q)
//   [68681728 , 68943872)  pden f32 [1024][64]
//   [68943872 , 69468160)  ctx  f32 [32][64][64]
//   [69468160 , 71565312)  W2T  bf16 [4][512][512]

typedef __attribute__((ext_vector_type(8))) __bf16 bf16x8;
typedef __attribute__((ext_vector_type(4))) __bf16 bf16x4;
typedef __attribute__((ext_vector_type(4))) float f32x4;

#define SQRT_DIM 22.627416997969522f

__device__ __forceinline__ void gload_lds16(const void* g, void* l) {
  __builtin_amdgcn_global_load_lds((__attribute__((address_space(1))) void*)g,
                                   (__attribute__((address_space(3))) void*)l, 16, 0, 0);
}

// ---------- K0: tiled transpose w_qkv [512][1536] f32 -> WqkvT [1536][512] bf16
__global__ __launch_bounds__(256) void wqkv_transpose(const float* __restrict__ in,
                                                      __bf16* __restrict__ out) {
  const int n0 = blockIdx.x * 64, k0 = blockIdx.y * 64;
  __shared__ float t[64][65];
  const int tid = threadIdx.x;
  const int r = tid >> 4, c4 = (tid & 15) * 4;
#pragma unroll
  for (int p = 0; p < 4; ++p) {
    float4 v = *(const float4*)(in + (size_t)(k0 + p * 16 + r) * 1536 + n0 + c4);
    t[p * 16 + r][c4 + 0] = v.x;
    t[p * 16 + r][c4 + 1] = v.y;
    t[p * 16 + r][c4 + 2] = v.z;
    t[p * 16 + r][c4 + 3] = v.w;
  }
  __syncthreads();
#pragma unroll
  for (int p = 0; p < 4; ++p) {
    int c = p * 256 + tid;
    int rn = c >> 4, cc = (c & 15) * 4;
    bf16x4 o;
#pragma unroll
    for (int j = 0; j < 4; ++j) o[j] = (__bf16)t[cc + j][rn];
    *(bf16x4*)(out + (size_t)(n0 + rn) * 512 + k0 + cc) = o;
  }
}

// ---------- K1: row L2-norm scale (x / max(||x||,1e-12) * w * sqrt(512)) -> bf16
__global__ __launch_bounds__(256) void rmsnorm_k(const float* __restrict__ x,
                                                 const float* __restrict__ w,
                                                 __bf16* __restrict__ out) {
  const int row = blockIdx.x * 4 + (threadIdx.x >> 6);
  const int lane = threadIdx.x & 63;
  const float4* xr = (const float4*)(x + (size_t)row * 512);
  float4 v0 = xr[lane], v1 = xr[lane + 64];
  float s = v0.x * v0.x + v0.y * v0.y + v0.z * v0.z + v0.w * v0.w +
            v1.x * v1.x + v1.y * v1.y + v1.z * v1.z + v1.w * v1.w;
#pragma unroll
  for (int m = 1; m < 64; m <<= 1) s += __shfl_xor(s, m);
  const float sc = SQRT_DIM / fmaxf(sqrtf(s), 1e-12f);
  const float4* wr4 = (const float4*)w;
  float4 w0 = wr4[lane], w1 = wr4[lane + 64];
  __bf16* o = out + (size_t)row * 512;
  bf16x4 a, b2;
  a[0] = (__bf16)(v0.x * sc * w0.x); a[1] = (__bf16)(v0.y * sc * w0.y);
  a[2] = (__bf16)(v0.z * sc * w0.z); a[3] = (__bf16)(v0.w * sc * w0.w);
  b2[0] = (__bf16)(v1.x * sc * w1.x); b2[1] = (__bf16)(v1.y * sc * w1.y);
  b2[2] = (__bf16)(v1.z * sc * w1.z); b2[3] = (__bf16)(v1.w * sc * w1.w);
  *(bf16x4*)(o + lane * 4) = a;
  *(bf16x4*)(o + 256 + lane * 4) = b2;
}

// ---------- GEMM1: counted-vmcnt pipelined (T2+T3+T4+T5), BM=256 BN=128 BK=64,
// 512 thr (8 waves, 4M x 2N), 2-K-tile-deep prefetch, raw barriers.
// A=xn[16384][512], BT=WqkvT[1536][512]. Cols<512: fused q-softmax -> QS.
// Cols>=512: k,v -> KV[16384][1024].
__global__ __launch_bounds__(512) void gemm8p(const __bf16* __restrict__ A,
                                              const __bf16* __restrict__ BT,
                                              __bf16* __restrict__ QS,
                                              __bf16* __restrict__ KV) {
  __shared__ __bf16 As[2][256 * 64];
  __shared__ __bf16 Bs[2][128 * 64];
  const int K = 512;
  const int NT = 8;
  const int NX = 12;
  const int tid = threadIdx.x;
  const int lane = tid & 63;
  const int wave = tid >> 6;
  const int wr = (wave >> 1) * 64;
  const int wc = (wave & 1) * 64;
  const int l15 = lane & 15, lg = lane >> 4;
  const int cpx = gridDim.x >> 3;
  const int fid = blockIdx.x;
  const int tile = (fid & 7) * cpx + (fid >> 3);
  const int my = tile / NX;
  const int m0 = my * 256;
  const int n0 = (tile - my * NX) * 128;

  f32x4 acc[4][4] = {};

  auto stage = [&](int buf, int k0) {
#pragma unroll
    for (int it = 0; it < 4; ++it) {
      int flat = it * 512 + tid;
      int row = flat >> 3;
      int cb = ((flat & 7) ^ (row & 7)) * 16;
      gload_lds16((const char*)(A + (size_t)(m0 + row) * K + k0) + cb,
                  (char*)(&As[buf][0]) + flat * 16);
    }
#pragma unroll
    for (int it = 0; it < 2; ++it) {
      int flat = it * 512 + tid;
      int row = flat >> 3;
      int cb = ((flat & 7) ^ (row & 7)) * 16;
      gload_lds16((const char*)(BT + (size_t)(n0 + row) * K + k0) + cb,
                  (char*)(&Bs[buf][0]) + flat * 16);
    }
  };

  stage(0, 0);
  stage(1, 64);
  asm volatile("s_waitcnt vmcnt(6)" ::: "memory");
  __builtin_amdgcn_s_barrier();

  for (int kt = 0; kt < NT; ++kt) {
    const int cur = kt & 1;
    bf16x8 a0[4], b0[4], a1[4], b1[4];
    const int sw0 = lg ^ (l15 & 7);
    const int sw1 = (4 + lg) ^ (l15 & 7);
#pragma unroll
    for (int i = 0; i < 4; ++i) {
      a0[i] = *(const bf16x8*)(&As[cur][(wr + i * 16 + l15) * 64 + sw0 * 8]);
      b0[i] = *(const bf16x8*)(&Bs[cur][(wc + i * 16 + l15) * 64 + sw0 * 8]);
      a1[i] = *(const bf16x8*)(&As[cur][(wr + i * 16 + l15) * 64 + sw1 * 8]);
      b1[i] = *(const bf16x8*)(&Bs[cur][(wc + i * 16 + l15) * 64 + sw1 * 8]);
    }
    asm volatile("s_waitcnt lgkmcnt(0)" ::: "memory");
    __builtin_amdgcn_sched_barrier(0);
    __builtin_amdgcn_s_barrier();
    if (kt + 2 < NT) stage(cur, (kt + 2) * 64);
    __builtin_amdgcn_s_setprio(1);
#pragma unroll
    for (int mi = 0; mi < 4; ++mi)
#pragma unroll
      for (int ni = 0; ni < 4; ++ni)
        acc[mi][ni] = __builtin_amdgcn_mfma_f32_16x16x32_bf16(a0[mi], b0[ni],
                                                              acc[mi][ni], 0, 0, 0);
    __builtin_amdgcn_s_setprio(0);
    __builtin_amdgcn_s_setprio(1);
#pragma unroll
    for (int mi = 0; mi < 4; ++mi)
#pragma unroll
      for (int ni = 0; ni < 4; ++ni)
        acc[mi][ni] = __builtin_amdgcn_mfma_f32_16x16x32_bf16(a1[mi], b1[ni],
                                                              acc[mi][ni], 0, 0, 0);
    __builtin_amdgcn_s_setprio(0);
    if (kt < NT - 1) {
      if (kt + 2 < NT)
        asm volatile("s_waitcnt vmcnt(6)" ::: "memory");
      else
        asm volatile("s_waitcnt vmcnt(0)" ::: "memory");
      __builtin_amdgcn_s_barrier();
    }
  }

  if (n0 < 512) {
    // fused q feature-softmax: each wave owns one head's 64 cols per row
#pragma unroll
    for (int mi = 0; mi < 4; ++mi)
#pragma unroll
      for (int r = 0; r < 4; ++r) {
        float v0_ = acc[mi][0][r], v1_ = acc[mi][1][r], v2_ = acc[mi][2][r],
              v3_ = acc[mi][3][r];
        float mx = fmaxf(fmaxf(v0_, v1_), fmaxf(v2_, v3_));
#pragma unroll
        for (int m = 1; m < 16; m <<= 1) mx = fmaxf(mx, __shfl_xor(mx, m));
        float e0 = __expf(v0_ - mx), e1 = __expf(v1_ - mx),
              e2 = __expf(v2_ - mx), e3 = __expf(v3_ - mx);
        float s = e0 + e1 + e2 + e3;
#pragma unroll
        for (int m = 1; m < 16; m <<= 1) s += __shfl_xor(s, m);
        float inv = 0.125f / s;  // * C^-0.5
        size_t rwb = (size_t)(m0 + wr + mi * 16 + lg * 4 + r) * 512 + n0 + wc;
        QS[rwb + l15] = (__bf16)(e0 * inv);
        QS[rwb + 16 + l15] = (__bf16)(e1 * inv);
        QS[rwb + 32 + l15] = (__bf16)(e2 * inv);
        QS[rwb + 48 + l15] = (__bf16)(e3 * inv);
      }
  } else {
#pragma unroll
    for (int mi = 0; mi < 4; ++mi)
#pragma unroll
      for (int ni = 0; ni < 4; ++ni) {
        int col = (n0 - 512) + wc + ni * 16 + l15;
#pragma unroll
        for (int r = 0; r < 4; ++r) {
          int rw = m0 + wr + mi * 16 + lg * 4 + r;
          KV[(size_t)rw * 1024 + col] = (__bf16)acc[mi][ni][r];
        }
      }
  }
}

// ---------- GEMM2 fused with bias + out-RMSNorm. BM=64 x BN=512(full rows) x BK=64.
// 512 thr = 8 N-waves (wc = wave*64), all waves share rows m0..m0+63.
// Same counted-vmcnt schedule and T2 swizzle as gemm8p (9 loads/thread/stage).
// Epilogue: v = acc + bias; rowwise sum(v^2) via 16-lane shfl + LDS cross-wave;
// out = v * (sqrt(512)/max(||row||,1e-12)) * onw  (f32, written directly).
__global__ __launch_bounds__(512) void gemm2rms(const __bf16* __restrict__ QS,
                                                const __bf16* __restrict__ W2T,
                                                const float* __restrict__ bias,
                                                const float* __restrict__ onw,
                                                float* __restrict__ out) {
  __shared__ __bf16 As[2][64 * 64];
  __shared__ __bf16 Bs[2][512 * 64];
  __shared__ float rss[64][8];
  const int K = 512;
  const int NT = 8;
  const int tid = threadIdx.x;
  const int lane = tid & 63;
  const int wave = tid >> 6;
  const int wc = wave * 64;
  const int l15 = lane & 15, lg = lane >> 4;
  const int cpx = gridDim.x >> 3;
  const int fid = blockIdx.x;
  const int tile = (fid & 7) * cpx + (fid >> 3);
  const int m0 = tile * 64;
  const __bf16* bt = W2T + (size_t)(m0 >> 12) * 262144;

  f32x4 acc[4][4] = {};

  auto stage = [&](int buf, int k0) {
    {  // A: 64 rows x 8 chunks = 512 = 1 per thread
      int flat = tid;
      int row = flat >> 3;
      int cb = ((flat & 7) ^ (row & 7)) * 16;
      gload_lds16((const char*)(QS + (size_t)(m0 + row) * K + k0) + cb,
                  (char*)(&As[buf][0]) + flat * 16);
    }
#pragma unroll
    for (int it = 0; it < 8; ++it) {  // B: 512 rows x 8 chunks
      int flat = it * 512 + tid;
      int row = flat >> 3;
      int cb = ((flat & 7) ^ (row & 7)) * 16;
      gload_lds16((const char*)(bt + (size_t)row * K + k0) + cb,
                  (char*)(&Bs[buf][0]) + flat * 16);
    }
  };

  stage(0, 0);
  stage(1, 64);
  asm volatile("s_waitcnt vmcnt(9)" ::: "memory");
  __builtin_amdgcn_s_barrier();

  for (int kt = 0; kt < NT; ++kt) {
    const int cur = kt & 1;
    bf16x8 a0[4], b0[4], a1[4], b1[4];
    const int sw0 = lg ^ (l15 & 7);
    const int sw1 = (4 + lg) ^ (l15 & 7);
#pragma unroll
    for (int i = 0; i < 4; ++i) {
      a0[i] = *(const bf16x8*)(&As[cur][(i * 16 + l15) * 64 + sw0 * 8]);
      b0[i] = *(const bf16x8*)(&Bs[cur][(wc + i * 16 + l15) * 64 + sw0 * 8]);
      a1[i] = *(const bf16x8*)(&As[cur][(i * 16 + l15) * 64 + sw1 * 8]);
      b1[i] = *(const bf16x8*)(&Bs[cur][(wc + i * 16 + l15) * 64 + sw1 * 8]);
    }
    asm volatile("s_waitcnt lgkmcnt(0)" ::: "memory");
    __builtin_amdgcn_sched_barrier(0);
    __builtin_amdgcn_s_barrier();
    if (kt + 2 < NT) stage(cur, (kt + 2) * 64);
    __builtin_amdgcn_s_setprio(1);
#pragma unroll
    for (int mi = 0; mi < 4; ++mi)
#pragma unroll
      for (int ni = 0; ni < 4; ++ni)
        acc[mi][ni] = __builtin_amdgcn_mfma_f32_16x16x32_bf16(a0[mi], b0[ni],
                                                              acc[mi][ni], 0, 0, 0);
    __builtin_amdgcn_s_setprio(0);
    __builtin_amdgcn_s_setprio(1);
#pragma unroll
    for (int mi = 0; mi < 4; ++mi)
#pragma unroll
      for (int ni = 0; ni < 4; ++ni)
        acc[mi][ni] = __builtin_amdgcn_mfma_f32_16x16x32_bf16(a1[mi], b1[ni],
                                                              acc[mi][ni], 0, 0, 0);
    __builtin_amdgcn_s_setprio(0);
    if (kt < NT - 1) {
      if (kt + 2 < NT)
        asm volatile("s_waitcnt vmcnt(9)" ::: "memory");
      else
        asm volatile("s_waitcnt vmcnt(0)" ::: "memory");
      __builtin_amdgcn_s_barrier();
    }
  }

  // ---- fused epilogue: bias + rmsnorm + f32 store
  float bv[4], wv[4];
#pragma unroll
  for (int ni = 0; ni < 4; ++ni) {
    int col = wc + ni * 16 + l15;
    bv[ni] = bias[col];
    wv[ni] = onw[col];
  }
  float vv[4][4][4];
#pragma unroll
  for (int mi = 0; mi < 4; ++mi)
#pragma unroll
    for (int ni = 0; ni < 4; ++ni)
#pragma unroll
      for (int r = 0; r < 4; ++r) vv[mi][ni][r] = acc[mi][ni][r] + bv[ni];
#pragma unroll
  for (int mi = 0; mi < 4; ++mi)
#pragma unroll
    for (int r = 0; r < 4; ++r) {
      float ps = vv[mi][0][r] * vv[mi][0][r] + vv[mi][1][r] * vv[mi][1][r] +
                 vv[mi][2][r] * vv[mi][2][r] + vv[mi][3][r] * vv[mi][3][r];
#pragma unroll
      for (int m = 1; m < 16; m <<= 1) ps += __shfl_xor(ps, m);
      if (l15 == 0) rss[mi * 16 + lg * 4 + r][wave] = ps;
    }
  __syncthreads();
#pragma unroll
  for (int mi = 0; mi < 4; ++mi)
#pragma unroll
    for (int r = 0; r < 4; ++r) {
      int row = mi * 16 + lg * 4 + r;
      float ss = rss[row][0] + rss[row][1] + rss[row][2] + rss[row][3] +
                 rss[row][4] + rss[row][5] + rss[row][6] + rss[row][7];
      float sc = SQRT_DIM / fmaxf(sqrtf(ss), 1e-12f);
      size_t rb = (size_t)(m0 + row) * 512;
#pragma unroll
      for (int ni = 0; ni < 4; ++ni)
        out[rb + wc + ni * 16 + l15] = vv[mi][ni][r] * sc * wv[ni];
    }
}

// ---------- K3: partial context: pctx[wg] = sum_tokens exp(k[d])*v[e]; pden = sum exp(k[d])
// 1024 blocks = bh(32) x chunk(32), 128 tokens per chunk. KV layout [16384][1024] (k|v).
__global__ __launch_bounds__(256) void ctx_partial(const __bf16* __restrict__ kv,
                                                   float* __restrict__ pctx,
                                                   float* __restrict__ pden) {
  const int wg = blockIdx.x;  // bh*32 + chunk
  const int bh = wg >> 5, chunk = wg & 31;
  const int b = bh >> 3, h = bh & 7;
  const int tid = threadIdx.x;
  __shared__ float ek[16][64];
  __shared__ float vv[16][64];
  float acc[4][4] = {};
  float dsum = 0.0f;
  const int td = (tid >> 4) * 4, te = (tid & 15) * 4;
  const int tokc = tid >> 4, rr = tid & 15;
  for (int t0 = 0; t0 < 128; t0 += 16) {
    __syncthreads();
    {
      int tok = b * 4096 + chunk * 128 + t0 + tokc;
      const __bf16* base = kv + (size_t)tok * 1024 + h * 64;  // k block
      if (rr < 8) {
        bf16x8 kx = *(const bf16x8*)(base + rr * 8);
#pragma unroll
        for (int j = 0; j < 8; ++j) ek[tokc][rr * 8 + j] = __expf((float)kx[j]);
      } else {
        bf16x8 vx = *(const bf16x8*)(base + 512 + (rr - 8) * 8);  // v block
#pragma unroll
        for (int j = 0; j < 8; ++j) vv[tokc][(rr - 8) * 8 + j] = (float)vx[j];
      }
    }
    __syncthreads();
#pragma unroll
    for (int t = 0; t < 16; ++t) {
      float4 a4 = *(const float4*)&ek[t][td];
      float4 b4 = *(const float4*)&vv[t][te];
      float aa[4] = {a4.x, a4.y, a4.z, a4.w};
      float bb[4] = {b4.x, b4.y, b4.z, b4.w};
#pragma unroll
      for (int i = 0; i < 4; ++i)
#pragma unroll
        for (int j = 0; j < 4; ++j) acc[i][j] += aa[i] * bb[j];
    }
    if (tid < 64) {
#pragma unroll
      for (int t = 0; t < 16; ++t) dsum += ek[t][tid];
    }
  }
  float* op = pctx + (size_t)wg * 4096;
#pragma unroll
  for (int i = 0; i < 4; ++i)
#pragma unroll
    for (int j = 0; j < 4; ++j) op[(td + i) * 64 + te + j] = acc[i][j];
  if (tid < 64) pden[wg * 64 + tid] = dsum;
}

// ---------- K4: finalize ctx with memory-KV and softmax denominator (32 chunks)
__global__ __launch_bounds__(256) void ctx_final(const float* __restrict__ pctx,
                                                 const float* __restrict__ pden,
                                                 const float* __restrict__ memkv,
                                                 float* __restrict__ ctx) {
  const int bh = blockIdx.x;  // 0..31
  const int h = bh & 7;
  const int tid = threadIdx.x;
  __shared__ float emk[64][8], mvl[64][8], den[64];
  if (tid < 64) {
    float d = 0.0f;
#pragma unroll
    for (int m = 0; m < 8; ++m) {
      float e = __expf(memkv[(size_t)h * 512 + tid * 8 + m]);
      emk[tid][m] = e;
      d += e;
      mvl[tid][m] = memkv[4096 + (size_t)h * 512 + tid * 8 + m];
    }
#pragma unroll
    for (int c = 0; c < 32; ++c) d += pden[((size_t)bh * 32 + c) * 64 + tid];
    den[tid] = d;
  }
  __syncthreads();
  const int td = (tid >> 4) * 4, te = (tid & 15) * 4;
#pragma unroll
  for (int i = 0; i < 4; ++i) {
    int dd = td + i;
    float invd = 1.0f / den[dd];
#pragma unroll
    for (int j = 0; j < 4; ++j) {
      int e = te + j;
      float s = 0.0f;
#pragma unroll
      for (int m = 0; m < 8; ++m) s += emk[dd][m] * mvl[e][m];
#pragma unroll
      for (int c = 0; c < 32; ++c)
        s += pctx[((size_t)bh * 32 + c) * 4096 + dd * 64 + e];
      ctx[(size_t)bh * 4096 + dd * 64 + e] = s * invd;
    }
  }
}

// ---------- K5: fold ctx into w_out: W2T[b][j][h*64+d] = sum_e ctx[b,h,d,e]*w_out[h*64+e][j]
__global__ __launch_bounds__(256) void make_w2t(const float* __restrict__ ctx,
                                                const float* __restrict__ wout,
                                                __bf16* __restrict__ W2T) {
  const int wg = blockIdx.x;  // b*32 + h*4 + jc
  const int b = wg >> 5, h = (wg >> 2) & 7, jc = wg & 3;
  const int j0 = jc * 128;
  const int tid = threadIdx.x;
  __shared__ float cs[64][65];
  __shared__ float wo[64][128];
  const float* ch = ctx + ((size_t)b * 8 + h) * 4096;
#pragma unroll
  for (int it = 0; it < 16; ++it) {
    int flat = it * 256 + tid;
    cs[flat >> 6][flat & 63] = ch[flat];
  }
#pragma unroll
  for (int it = 0; it < 32; ++it) {
    int flat = it * 256 + tid;
    int e = flat >> 7, j = flat & 127;
    wo[e][j] = wout[(size_t)(h * 64 + e) * 512 + j0 + j];
  }
  __syncthreads();
  const int d = tid & 63;
  const int jg = (tid >> 6) * 32;
  for (int jj = 0; jj < 32; ++jj) {
    int j = jg + jj;
    float s = 0.0f;
#pragma unroll
    for (int e = 0; e < 64; ++e) s += cs[d][e] * wo[e][j];
    W2T[(size_t)b * 262144 + (size_t)(j0 + j) * 512 + h * 64 + d] = (__bf16)s;
  }
}

extern "C" void kernel_launch(void* const* d_in, const int* in_sizes, int n_in,
                              void* d_out, int out_size, void* d_ws, size_t ws_size,
                              hipStream_t stream) {
  const float* x = (const float*)d_in[0];
  const float* norm_w = (const float*)d_in[1];
  const float* w_qkv = (const float*)d_in[2];
  const float* mem_kv = (const float*)d_in[3];
  const float* w_out = (const float*)d_in[4];
  const float* b_out = (const float*)d_in[5];
  const float* onw = (const float*)d_in[6];

  char* ws = (char*)d_ws;
  __bf16* xn = (__bf16*)(ws + 0);            // 16 MB (region0)
  float* pctx = (float*)(ws + 0);            // 16 MB (region0, xn dead after GEMM1)
  __bf16* WqkvT = (__bf16*)(ws + 16777216);  // 1.5 MB
  __bf16* KV = (__bf16*)(ws + 18350080);     // 32 MB
  __bf16* QS = (__bf16*)(ws + 51904512);     // 16 MB
  float* pden = (float*)(ws + 68681728);     // 256 KB
  float* ctx = (float*)(ws + 68943872);      // 512 KB
  __bf16* W2T = (__bf16*)(ws + 69468160);    // 2 MB

  wqkv_transpose<<<dim3(24, 8), 256, 0, stream>>>(w_qkv, WqkvT);
  rmsnorm_k<<<4096, 256, 0, stream>>>(x, norm_w, xn);
  gemm8p<<<768, 512, 0, stream>>>(xn, WqkvT, QS, KV);
  ctx_partial<<<1024, 256, 0, stream>>>(KV, pctx, pden);
  ctx_final<<<32, 256, 0, stream>>>(pctx, pden, mem_kv, ctx);
  make_w2t<<<128, 256, 0, stream>>>(ctx, w_out, W2T);
  gemm2rms<<<256, 512, 0, stream>>>(QS, W2T, b_out, onw, (float*)d_out);
}